// Round 14
// baseline (1103.281 us; speedup 1.0000x reference)
//
#include <hip/hip_runtime.h>

// VQ-VAE VectorQuantizer forward + EMA update, MI355X (gfx950).
// Distance argmin bit-exactly emulates the numpy fp32 reference:
//   dist = pairwise_sum(x*x) - 2*(sgemm single-FMA-chain) + pairwise_sum(w*w)
// R2-R8: fp32 K-split GEMM ladder -> 810us k_argmin. R10-R13 (MFMA filter):
//   fixed 1043us env wall, abandoned. R14: fence-based fusion REGRESSED.
// R15: 8-row d-chunks (16KB LDS dbuf) -> k_argmin 799us, total 1088. BEST.
// R16: R15 compute verbatim + fence-free launch fusion (aux tail = 289us
//   vs ~60us roofline; 10 dispatches -> 6):
//   - k_prep: tr(z)+tr(w)+rownorm(z)+rownorm(w), one 7680-block launch
//     (block-index branch, bodies verbatim, no cross-part deps).
//   - k_nsum folded into k_neww: every block recomputes nsum with the
//     byte-identical reduction order (deterministic => same value, bit-
//     exact); block 0 finalizes OFF_LOSS. Serial 1-block kernel removed.
//   k_argmin / k_reduce / k_init / k_scatter byte-identical to R15.

#define NTOK 16384
#define KC   8192
#define DD   256

#define OFF_Q    0
#define OFF_LOSS 4194304
#define OFF_IDX  4194305
#define OFF_W    4210689
#define OFF_CS   6307841
#define OFF_EMA  6316033

#define DECAY_F  0.99f
#define OMD_F    0.01f
#define EPS_F    1e-5f
#define KEPS_F   0.08192f   // K * eps

#define SPLIT    16
#define NSTEP    128        // 4 code-tiles x 32 8-row d-chunks

typedef __attribute__((address_space(3))) unsigned int lds_u;
typedef const __attribute__((address_space(1))) unsigned int glob_u;
typedef float v2f __attribute__((ext_vector_type(2)));
typedef union { float4 f4; v2f h[2]; } f4u;

// ---------------- fused prep: 2 transposes + 2 row-norms -------------------
// blocks [0,4096): tr z->zT; [4096,6144): tr w->wT;
// [6144,7168): rownorm z->x2v; [7168,7680): rownorm w->w2v.
// Bodies verbatim from the passing R15 kernels (bit-exact).
__global__ __launch_bounds__(256) void k_prep(const float* __restrict__ z,
                                              const float* __restrict__ w,
                                              float* __restrict__ zT,
                                              float* __restrict__ wT,
                                              float* __restrict__ x2v,
                                              float* __restrict__ w2v) {
    __shared__ float s[32][33];
    const int b = blockIdx.x, tid = threadIdx.x;

    if (b < 6144) {
        // ---- 32x32 LDS transpose (coalesced both sides) ----
        const float* in;
        float* outT;
        int R, bx, by;
        if (b < 4096) { in = z; outT = zT; R = NTOK; bx = b & 7; by = b >> 3; }
        else { const int b2 = b - 4096;
               in = w; outT = wT; R = KC;   bx = b2 & 7; by = b2 >> 3; }
        const int tx = tid & 31, ty = tid >> 5;
        const int c0 = bx * 32, r0 = by * 32;
        #pragma unroll
        for (int i = 0; i < 4; ++i)
            s[ty + i * 8][tx] = in[(size_t)(r0 + ty + i * 8) * DD + c0 + tx];
        __syncthreads();
        #pragma unroll
        for (int i = 0; i < 4; ++i)
            outT[(size_t)(c0 + ty + i * 8) * R + r0 + tx] = s[tx][ty + i * 8];
    } else {
        // ---- numpy-pairwise row squared-norms (n=256): bit-exact ----
        const float* a;
        float* outn;
        int blk;
        if (b < 7168) { a = z; outn = x2v; blk = b - 6144; }
        else          { a = w; outn = w2v; blk = b - 7168; }
        const int wave = tid >> 6, lane = tid & 63;
        const int row  = blk * 16 + wave * 4 + (lane >> 4);
        const int p    = lane & 15;
        const int h    = p >> 3, j = p & 7;
        const float* base = a + row * DD + h * 128 + j;
        float v = base[0];
        float r = __fmul_rn(v, v);
        #pragma unroll
        for (int t = 1; t < 16; ++t) {
            v = base[8 * t];
            r = __fadd_rn(r, __fmul_rn(v, v));
        }
        r = __fadd_rn(r, __shfl_xor(r, 1));
        r = __fadd_rn(r, __shfl_xor(r, 2));
        r = __fadd_rn(r, __shfl_xor(r, 4));
        r = __fadd_rn(r, __shfl_xor(r, 8));
        if (p == 0) outn[row] = r;
    }
}

// ---------------- argmin: K-split fp32 GEMM, 128 rows x 128 codes/tile -----
// grid = 2048: split = blockIdx&15 (split&7 = XCD id), rb = blockIdx>>4.
// 128 steps of 8-row d-chunks (16KB LDS dbuf), one __syncthreads per step.
// 8x8 acc as v2f pairs via v_pk_fma_f32 (two independent IEEE fp32 FMAs,
// rounding == v_fma_f32; k-chain ascending => bit-exact).
__global__ __launch_bounds__(256, 4) void k_argmin(
        const float* __restrict__ zT, const float* __restrict__ wT,
        const float* __restrict__ x2v, const float* __restrict__ w2v,
        float* __restrict__ vbuf, int* __restrict__ kbuf) {
    __shared__ float Zs[2][8][128];    // [buf][d][row]  2 x 4 KB
    __shared__ float Ws[2][8][128];    // [buf][d][code] 2 x 4 KB

    const int tid   = threadIdx.x;
    const int split = blockIdx.x & 15;
    const int rb    = blockIdx.x >> 4;
    const int n0    = rb * 128;
    const int cbase = split * 512;
    const int tx4   = (tid & 15) * 4;
    const int ty4   = (tid >> 4) * 4;
    const int l     = tid & 63;
    const int wv    = tid >> 6;
    const int col   = (l & 31) * 4;

    float bestv[8];
    int   bestk[8];
    #pragma unroll
    for (int i = 0; i < 8; ++i) { bestv[i] = 1e30f; bestk[i] = 0; }

    v2f acc[8][4];

    // stage step s into buffer b: 1 gz + 1 gw global_load_lds per thread
    auto stage = [&](int s, int b) {
        const int d0 = (s & 31) * 8;
        const int c0 = cbase + (s >> 5) * 128;
        const int rr = wv * 2 + (l >> 5);   // per-lane d-row
        const float* gz = zT + (size_t)(d0 + rr) * NTOK + n0 + col;
        const float* gw = wT + (size_t)(d0 + rr) * KC   + c0 + col;
        __builtin_amdgcn_global_load_lds(
            (glob_u*)gz,
            (lds_u*)((char*)&Zs[b][0][0] + wv * 1024 + l * 16), 16, 0, 0);
        __builtin_amdgcn_global_load_lds(
            (glob_u*)gw,
            (lds_u*)((char*)&Ws[b][0][0] + wv * 1024 + l * 16), 16, 0, 0);
    };

    stage(0, 0);
    __syncthreads();

    for (int s = 0; s < NSTEP; ++s) {
        const int cur = s & 1;

        if ((s & 31) == 0) {
            #pragma unroll
            for (int i = 0; i < 8; ++i)
                #pragma unroll
                for (int jp = 0; jp < 4; ++jp) acc[i][jp] = (v2f)(0.0f);
        }

        if (s + 1 < NSTEP) stage(s + 1, cur ^ 1);   // prefetch next chunk

        #pragma unroll 8
        for (int dd = 0; dd < 8; ++dd) {
            f4u A0, A1, B0, B1;
            A0.f4 = *(const float4*)&Zs[cur][dd][ty4];
            A1.f4 = *(const float4*)&Zs[cur][dd][64 + ty4];
            B0.f4 = *(const float4*)&Ws[cur][dd][tx4];
            B1.f4 = *(const float4*)&Ws[cur][dd][64 + tx4];
            // v_pk_fma_f32: A-broadcast via op_sel (no splat movs).
#define PKLO(ACC, A, B) asm("v_pk_fma_f32 %0, %1, %2, %0 op_sel:[0,0,0] op_sel_hi:[0,1,1]" \
                            : "+v"(ACC) : "v"(A), "v"(B))
#define PKHI(ACC, A, B) asm("v_pk_fma_f32 %0, %1, %2, %0 op_sel:[1,0,0] op_sel_hi:[1,1,1]" \
                            : "+v"(ACC) : "v"(A), "v"(B))
#define PK4(MAC, I, AP)                \
            MAC(acc[I][0], AP, B0.h[0]); \
            MAC(acc[I][1], AP, B0.h[1]); \
            MAC(acc[I][2], AP, B1.h[0]); \
            MAC(acc[I][3], AP, B1.h[1]);
            PK4(PKLO, 0, A0.h[0])
            PK4(PKHI, 1, A0.h[0])
            PK4(PKLO, 2, A0.h[1])
            PK4(PKHI, 3, A0.h[1])
            PK4(PKLO, 4, A1.h[0])
            PK4(PKHI, 5, A1.h[0])
            PK4(PKLO, 6, A1.h[1])
            PK4(PKHI, 7, A1.h[1])
#undef PK4
#undef PKHI
#undef PKLO
        }

        if ((s & 31) == 31) {
            // dist = (x2 - 2*xe) + w2, per-op fp32 rounding; explicit (==, k<)
            // tie-break == np.argmin first-occurrence.
            const int c0 = cbase + (s >> 5) * 128;
            #pragma unroll
            for (int j = 0; j < 8; ++j) {
                const int   jp   = j >> 1;
                const int   code = c0 + ((j < 4) ? (tx4 + j) : (64 + tx4 + j - 4));
                const float w2   = w2v[code];
                #pragma unroll
                for (int i = 0; i < 8; ++i) {
                    const int   row = n0 + ((i < 4) ? (ty4 + i) : (64 + ty4 + i - 4));
                    const float x2  = x2v[row];
                    const float xe  = (j & 1) ? acc[i][jp].y : acc[i][jp].x;
                    const float dv  = __fadd_rn(
                        __fsub_rn(x2, __fmul_rn(2.0f, xe)), w2);
                    if (dv < bestv[i] || (dv == bestv[i] && code < bestk[i])) {
                        bestv[i] = dv; bestk[i] = code;
                    }
                }
            }
        }

        __syncthreads();   // drains prefetch vmcnt + LDS reads
    }

    // reduce across tx (16 consecutive lanes share ty)
    #pragma unroll
    for (int i = 0; i < 8; ++i) {
        float bv = bestv[i];
        int   bk = bestk[i];
        #pragma unroll
        for (int off = 8; off; off >>= 1) {
            const float ov = __shfl_down(bv, off, 16);
            const int   ok = __shfl_down(bk, off, 16);
            if (ov < bv || (ov == bv && ok < bk)) { bv = ov; bk = ok; }
        }
        if ((tid & 15) == 0) {
            const int row = n0 + ((i < 4) ? (ty4 + i) : (64 + ty4 + i - 4));
            vbuf[split * NTOK + row] = bv;
            kbuf[split * NTOK + row] = bk;
        }
    }
}

// ---------------- combine the 16 split-candidates per row ------------------
__global__ __launch_bounds__(256) void k_reduce(const float* __restrict__ vbuf,
                                                const int* __restrict__ kbuf,
                                                int* __restrict__ idx_ws,
                                                float* __restrict__ out) {
    const int r = blockIdx.x * 256 + threadIdx.x;
    float bv = vbuf[r];
    int   bk = kbuf[r];
    #pragma unroll
    for (int s = 1; s < SPLIT; ++s) {
        const float v = vbuf[s * NTOK + r];
        const int   k = kbuf[s * NTOK + r];
        if (v < bv || (v == bv && k < bk)) { bv = v; bk = k; }
    }
    idx_ws[r] = bk;
    out[OFF_IDX + r] = (float)bk;
}

// ---------------- init EMA outputs + zero loss accumulator -----------------
// (runs AFTER k_reduce: OFF_EMA region doubles as vbuf/kbuf scratch)
__global__ __launch_bounds__(256) void k_init(const float* __restrict__ emaw,
                                              const float* __restrict__ ecs,
                                              float* __restrict__ out,
                                              float* __restrict__ lossacc) {
    const int i = blockIdx.x * 256 + threadIdx.x;    // grid covers KC*DD = 2M
    out[OFF_EMA + i] = __fmul_rn(DECAY_F, emaw[i]);
    if (i < KC) out[OFF_CS + i] = __fmul_rn(DECAY_F, ecs[i]);
    if (i == 0) *lossacc = 0.0f;
}

// ---------------- gather quantized + loss partial + EMA scatter ------------
__global__ __launch_bounds__(256) void k_scatter(const float* __restrict__ z,
                                                 const float* __restrict__ w,
                                                 const int* __restrict__ idx_ws,
                                                 float* __restrict__ out,
                                                 float* __restrict__ lossacc) {
    const int n = blockIdx.x, d = threadIdx.x;
    const int k = idx_ws[n];
    const float zv   = z[n * DD + d];
    const float q    = w[k * DD + d];
    const float diff = __fsub_rn(q, zv);
    out[OFF_Q + n * DD + d] = __fadd_rn(zv, diff);   // straight-through value

    float s = __fmul_rn(diff, diff);
    #pragma unroll
    for (int off = 32; off; off >>= 1) s += __shfl_down(s, off, 64);
    __shared__ float ps[4];
    if ((d & 63) == 0) ps[d >> 6] = s;
    __syncthreads();
    if (d == 0) atomicAdd(lossacc, ps[0] + ps[1] + ps[2] + ps[3]);

    atomicAdd(&out[OFF_EMA + k * DD + d], __fmul_rn(OMD_F, zv));
    if (d == 0) atomicAdd(&out[OFF_CS + k], OMD_F);
}

// ---------- new_weight + fused nsum/loss (nsum recomputed per block) -------
// Each block computes nsum with the byte-identical order of the old k_nsum
// (strided loads + shfl + ((ps0+ps1)+ps2)+ps3) => deterministic, same value
// in every block, bit-exact. Block 0 also finalizes OFF_LOSS.
__global__ __launch_bounds__(256) void k_neww(float* __restrict__ out,
                                              const float* __restrict__ lossacc) {
    const int k = blockIdx.x, d = threadIdx.x;
    float s = 0.0f;
    for (int i = d; i < KC; i += 256) s += out[OFF_CS + i];
    #pragma unroll
    for (int off = 32; off; off >>= 1) s += __shfl_down(s, off, 64);
    __shared__ float ps[4];
    if ((d & 63) == 0) ps[d >> 6] = s;
    __syncthreads();
    const float n = ps[0] + ps[1] + ps[2] + ps[3];
    if (k == 0 && d == 0)
        out[OFF_LOSS] = 1.25f * (*lossacc) / 4194304.0f;

    const float cs = __fmul_rn(__fdiv_rn(__fadd_rn(out[OFF_CS + k], EPS_F),
                                         __fadd_rn(n, KEPS_F)), n);
    out[OFF_W + k * DD + d] = __fdiv_rn(out[OFF_EMA + k * DD + d], cs);
}

extern "C" void kernel_launch(void* const* d_in, const int* in_sizes, int n_in,
                              void* d_out, int out_size, void* d_ws, size_t ws_size,
                              hipStream_t stream) {
    const float* z    = (const float*)d_in[0];
    const float* w    = (const float*)d_in[1];
    const float* ecs  = (const float*)d_in[2];
    const float* emaw = (const float*)d_in[3];
    float* out = (float*)d_out;

    // small scratch in ws (same footprint that always passed)
    int*   idx_ws  = (int*)d_ws;                       // NTOK ints
    float* x2v     = (float*)d_ws + NTOK;              // NTOK floats
    float* w2v     = x2v + NTOK;                       // KC floats
    float* lossacc = w2v + KC;                         // 1 float

    // big scratch inside not-yet-final d_out regions:
    float* zT   = out + OFF_Q;     // 16384x256 -> 256x16384 (16 MB)
    float* wT   = out + OFF_W;     //  8192x256 -> 256x8192  ( 8 MB)
    float* vbuf = out + OFF_EMA;                        // SPLIT*NTOK floats
    int*   kbuf = (int*)(out + OFF_EMA) + SPLIT * NTOK; // SPLIT*NTOK ints

    k_prep   <<<7680,  256, 0, stream>>>(z, w, zT, wT, x2v, w2v);
    k_argmin <<<SPLIT * (NTOK / 128), 256, 0, stream>>>(zT, wT, x2v, w2v,
                                                        vbuf, kbuf);
    k_reduce <<<NTOK / 256, 256, 0, stream>>>(vbuf, kbuf, idx_ws, out);
    k_init   <<<(KC * DD) / 256, 256, 0, stream>>>(emaw, ecs, out, lossacc);
    k_scatter<<<NTOK,  256, 0, stream>>>(z, w, idx_ws, out, lossacc);
    k_neww   <<<KC,    256, 0, stream>>>(out, lossacc);
}

// Round 15
// 1073.426 us; speedup vs baseline: 1.0278x; 1.0278x over previous
//
#include <hip/hip_runtime.h>

// VQ-VAE VectorQuantizer forward + EMA update, MI355X (gfx950).
// Distance argmin bit-exactly emulates the numpy fp32 reference:
//   dist = pairwise_sum(x*x) - 2*(sgemm single-FMA-chain) + pairwise_sum(w*w)
// R2-R8: fp32 K-split GEMM ladder -> 810us. R10-R13 (MFMA filter): 1043us
//   env wall, abandoned. R14: fence fusion REGRESSED. R15: 8-row d-chunks
//   -> argmin 799, total 1088 (best). R16: fence-free launch fusion ~0
//   (aux is kernel time, not gaps): k_tr(z) alone ~81us, issue-bound
//   (4B/thread scalar loads).
// R17: (a) float4 transposes in k_prep (4x fewer mem instructions);
//   (b) SPLIT 16->32 (grid 4096, 2 code-tiles/block, NSTEP 64) to halve
//   the dispatch-tail waste (2048 blocks = 2.67 fill rounds at 3
//   blocks/CU; last partial round idles ~1/3 machine). Chain order per
//   (row,code) unchanged (d ascending within its kt-tile) => bit-exact.
//   zT FETCH doubles (~560MB) — R2 demonstrated 682GB/s on this path.

#define NTOK 16384
#define KC   8192
#define DD   256

#define OFF_Q    0
#define OFF_LOSS 4194304
#define OFF_IDX  4194305
#define OFF_W    4210689
#define OFF_CS   6307841
#define OFF_EMA  6316033

#define DECAY_F  0.99f
#define OMD_F    0.01f
#define EPS_F    1e-5f
#define KEPS_F   0.08192f   // K * eps

#define SPLIT    32
#define NSTEP    64         // 2 code-tiles x 32 8-row d-chunks

typedef __attribute__((address_space(3))) unsigned int lds_u;
typedef const __attribute__((address_space(1))) unsigned int glob_u;
typedef float v2f __attribute__((ext_vector_type(2)));
typedef union { float4 f4; v2f h[2]; } f4u;

// ---------------- fused prep: 2 transposes (float4) + 2 row-norms ----------
// blocks [0,4096): tr z->zT; [4096,6144): tr w->wT;
// [6144,7168): rownorm z->x2v; [7168,7680): rownorm w->w2v.
__global__ __launch_bounds__(256) void k_prep(const float* __restrict__ z,
                                              const float* __restrict__ w,
                                              float* __restrict__ zT,
                                              float* __restrict__ wT,
                                              float* __restrict__ x2v,
                                              float* __restrict__ w2v) {
    __shared__ float s[32][33];
    const int b = blockIdx.x, tid = threadIdx.x;

    if (b < 6144) {
        // ---- 32x32 float4 transpose: 1 float4 load + 1 float4 store/thread
        const float* in;
        float* outT;
        int R, bx, by;
        if (b < 4096) { in = z; outT = zT; R = NTOK; bx = b & 7; by = b >> 3; }
        else { const int b2 = b - 4096;
               in = w; outT = wT; R = KC;   bx = b2 & 7; by = b2 >> 3; }
        const int c0 = bx * 32, r0 = by * 32;
        {
            const int r = tid >> 3, c4 = (tid & 7) * 4;
            const float4 v4 = *(const float4*)&in[(size_t)(r0 + r) * DD + c0 + c4];
            s[r][c4 + 0] = v4.x;
            s[r][c4 + 1] = v4.y;
            s[r][c4 + 2] = v4.z;
            s[r][c4 + 3] = v4.w;
        }
        __syncthreads();
        {
            const int c = tid >> 3, r4 = (tid & 7) * 4;
            float4 w4;
            w4.x = s[r4 + 0][c];
            w4.y = s[r4 + 1][c];
            w4.z = s[r4 + 2][c];
            w4.w = s[r4 + 3][c];
            *(float4*)&outT[(size_t)(c0 + c) * R + r0 + r4] = w4;
        }
    } else {
        // ---- numpy-pairwise row squared-norms (n=256): bit-exact ----
        const float* a;
        float* outn;
        int blk;
        if (b < 7168) { a = z; outn = x2v; blk = b - 6144; }
        else          { a = w; outn = w2v; blk = b - 7168; }
        const int wave = tid >> 6, lane = tid & 63;
        const int row  = blk * 16 + wave * 4 + (lane >> 4);
        const int p    = lane & 15;
        const int h    = p >> 3, j = p & 7;
        const float* base = a + row * DD + h * 128 + j;
        float v = base[0];
        float r = __fmul_rn(v, v);
        #pragma unroll
        for (int t = 1; t < 16; ++t) {
            v = base[8 * t];
            r = __fadd_rn(r, __fmul_rn(v, v));
        }
        r = __fadd_rn(r, __shfl_xor(r, 1));
        r = __fadd_rn(r, __shfl_xor(r, 2));
        r = __fadd_rn(r, __shfl_xor(r, 4));
        r = __fadd_rn(r, __shfl_xor(r, 8));
        if (p == 0) outn[row] = r;
    }
}

// ---------------- argmin: K-split fp32 GEMM, 128 rows x 128 codes/tile -----
// grid = 4096: split = blockIdx&31 (split&7 = XCD id), rb = blockIdx>>5.
// 64 steps of 8-row d-chunks (16KB LDS dbuf), one __syncthreads per step.
// 8x8 acc as v2f pairs via v_pk_fma_f32 (two independent IEEE fp32 FMAs,
// rounding == v_fma_f32; k-chain ascending => bit-exact).
__global__ __launch_bounds__(256, 4) void k_argmin(
        const float* __restrict__ zT, const float* __restrict__ wT,
        const float* __restrict__ x2v, const float* __restrict__ w2v,
        float* __restrict__ vbuf, int* __restrict__ kbuf) {
    __shared__ float Zs[2][8][128];    // [buf][d][row]  2 x 4 KB
    __shared__ float Ws[2][8][128];    // [buf][d][code] 2 x 4 KB

    const int tid   = threadIdx.x;
    const int split = blockIdx.x & 31;
    const int rb    = blockIdx.x >> 5;
    const int n0    = rb * 128;
    const int cbase = split * 256;
    const int tx4   = (tid & 15) * 4;
    const int ty4   = (tid >> 4) * 4;
    const int l     = tid & 63;
    const int wv    = tid >> 6;
    const int col   = (l & 31) * 4;

    float bestv[8];
    int   bestk[8];
    #pragma unroll
    for (int i = 0; i < 8; ++i) { bestv[i] = 1e30f; bestk[i] = 0; }

    v2f acc[8][4];

    // stage step s into buffer b: 1 gz + 1 gw global_load_lds per thread
    auto stage = [&](int s, int b) {
        const int d0 = (s & 31) * 8;
        const int c0 = cbase + (s >> 5) * 128;
        const int rr = wv * 2 + (l >> 5);   // per-lane d-row
        const float* gz = zT + (size_t)(d0 + rr) * NTOK + n0 + col;
        const float* gw = wT + (size_t)(d0 + rr) * KC   + c0 + col;
        __builtin_amdgcn_global_load_lds(
            (glob_u*)gz,
            (lds_u*)((char*)&Zs[b][0][0] + wv * 1024 + l * 16), 16, 0, 0);
        __builtin_amdgcn_global_load_lds(
            (glob_u*)gw,
            (lds_u*)((char*)&Ws[b][0][0] + wv * 1024 + l * 16), 16, 0, 0);
    };

    stage(0, 0);
    __syncthreads();

    for (int s = 0; s < NSTEP; ++s) {
        const int cur = s & 1;

        if ((s & 31) == 0) {
            #pragma unroll
            for (int i = 0; i < 8; ++i)
                #pragma unroll
                for (int jp = 0; jp < 4; ++jp) acc[i][jp] = (v2f)(0.0f);
        }

        if (s + 1 < NSTEP) stage(s + 1, cur ^ 1);   // prefetch next chunk

        #pragma unroll 8
        for (int dd = 0; dd < 8; ++dd) {
            f4u A0, A1, B0, B1;
            A0.f4 = *(const float4*)&Zs[cur][dd][ty4];
            A1.f4 = *(const float4*)&Zs[cur][dd][64 + ty4];
            B0.f4 = *(const float4*)&Ws[cur][dd][tx4];
            B1.f4 = *(const float4*)&Ws[cur][dd][64 + tx4];
            // v_pk_fma_f32: A-broadcast via op_sel (no splat movs).
#define PKLO(ACC, A, B) asm("v_pk_fma_f32 %0, %1, %2, %0 op_sel:[0,0,0] op_sel_hi:[0,1,1]" \
                            : "+v"(ACC) : "v"(A), "v"(B))
#define PKHI(ACC, A, B) asm("v_pk_fma_f32 %0, %1, %2, %0 op_sel:[1,0,0] op_sel_hi:[1,1,1]" \
                            : "+v"(ACC) : "v"(A), "v"(B))
#define PK4(MAC, I, AP)                \
            MAC(acc[I][0], AP, B0.h[0]); \
            MAC(acc[I][1], AP, B0.h[1]); \
            MAC(acc[I][2], AP, B1.h[0]); \
            MAC(acc[I][3], AP, B1.h[1]);
            PK4(PKLO, 0, A0.h[0])
            PK4(PKHI, 1, A0.h[0])
            PK4(PKLO, 2, A0.h[1])
            PK4(PKHI, 3, A0.h[1])
            PK4(PKLO, 4, A1.h[0])
            PK4(PKHI, 5, A1.h[0])
            PK4(PKLO, 6, A1.h[1])
            PK4(PKHI, 7, A1.h[1])
#undef PK4
#undef PKHI
#undef PKLO
        }

        if ((s & 31) == 31) {
            // dist = (x2 - 2*xe) + w2, per-op fp32 rounding; explicit (==, k<)
            // tie-break == np.argmin first-occurrence.
            const int c0 = cbase + (s >> 5) * 128;
            #pragma unroll
            for (int j = 0; j < 8; ++j) {
                const int   jp   = j >> 1;
                const int   code = c0 + ((j < 4) ? (tx4 + j) : (64 + tx4 + j - 4));
                const float w2   = w2v[code];
                #pragma unroll
                for (int i = 0; i < 8; ++i) {
                    const int   row = n0 + ((i < 4) ? (ty4 + i) : (64 + ty4 + i - 4));
                    const float x2  = x2v[row];
                    const float xe  = (j & 1) ? acc[i][jp].y : acc[i][jp].x;
                    const float dv  = __fadd_rn(
                        __fsub_rn(x2, __fmul_rn(2.0f, xe)), w2);
                    if (dv < bestv[i] || (dv == bestv[i] && code < bestk[i])) {
                        bestv[i] = dv; bestk[i] = code;
                    }
                }
            }
        }

        __syncthreads();   // drains prefetch vmcnt + LDS reads
    }

    // reduce across tx (16 consecutive lanes share ty)
    #pragma unroll
    for (int i = 0; i < 8; ++i) {
        float bv = bestv[i];
        int   bk = bestk[i];
        #pragma unroll
        for (int off = 8; off; off >>= 1) {
            const float ov = __shfl_down(bv, off, 16);
            const int   ok = __shfl_down(bk, off, 16);
            if (ov < bv || (ov == bv && ok < bk)) { bv = ov; bk = ok; }
        }
        if ((tid & 15) == 0) {
            const int row = n0 + ((i < 4) ? (ty4 + i) : (64 + ty4 + i - 4));
            vbuf[split * NTOK + row] = bv;
            kbuf[split * NTOK + row] = bk;
        }
    }
}

// ---------------- combine the 32 split-candidates per row ------------------
__global__ __launch_bounds__(256) void k_reduce(const float* __restrict__ vbuf,
                                                const int* __restrict__ kbuf,
                                                int* __restrict__ idx_ws,
                                                float* __restrict__ out) {
    const int r = blockIdx.x * 256 + threadIdx.x;
    float bv = vbuf[r];
    int   bk = kbuf[r];
    #pragma unroll
    for (int s = 1; s < SPLIT; ++s) {
        const float v = vbuf[s * NTOK + r];
        const int   k = kbuf[s * NTOK + r];
        if (v < bv || (v == bv && k < bk)) { bv = v; bk = k; }
    }
    idx_ws[r] = bk;
    out[OFF_IDX + r] = (float)bk;
}

// ---------------- init EMA outputs + zero loss accumulator -----------------
// (runs AFTER k_reduce: OFF_EMA region doubles as vbuf/kbuf scratch)
__global__ __launch_bounds__(256) void k_init(const float* __restrict__ emaw,
                                              const float* __restrict__ ecs,
                                              float* __restrict__ out,
                                              float* __restrict__ lossacc) {
    const int i = blockIdx.x * 256 + threadIdx.x;    // grid covers KC*DD = 2M
    out[OFF_EMA + i] = __fmul_rn(DECAY_F, emaw[i]);
    if (i < KC) out[OFF_CS + i] = __fmul_rn(DECAY_F, ecs[i]);
    if (i == 0) *lossacc = 0.0f;
}

// ---------------- gather quantized + loss partial + EMA scatter ------------
__global__ __launch_bounds__(256) void k_scatter(const float* __restrict__ z,
                                                 const float* __restrict__ w,
                                                 const int* __restrict__ idx_ws,
                                                 float* __restrict__ out,
                                                 float* __restrict__ lossacc) {
    const int n = blockIdx.x, d = threadIdx.x;
    const int k = idx_ws[n];
    const float zv   = z[n * DD + d];
    const float q    = w[k * DD + d];
    const float diff = __fsub_rn(q, zv);
    out[OFF_Q + n * DD + d] = __fadd_rn(zv, diff);   // straight-through value

    float s = __fmul_rn(diff, diff);
    #pragma unroll
    for (int off = 32; off; off >>= 1) s += __shfl_down(s, off, 64);
    __shared__ float ps[4];
    if ((d & 63) == 0) ps[d >> 6] = s;
    __syncthreads();
    if (d == 0) atomicAdd(lossacc, ps[0] + ps[1] + ps[2] + ps[3]);

    atomicAdd(&out[OFF_EMA + k * DD + d], __fmul_rn(OMD_F, zv));
    if (d == 0) atomicAdd(&out[OFF_CS + k], OMD_F);
}

// ---------- new_weight + fused nsum/loss (nsum recomputed per block) -------
// Each block computes nsum with the byte-identical order of the old k_nsum
// (strided loads + shfl + ((ps0+ps1)+ps2)+ps3) => deterministic, same value
// in every block, bit-exact. Block 0 also finalizes OFF_LOSS.
__global__ __launch_bounds__(256) void k_neww(float* __restrict__ out,
                                              const float* __restrict__ lossacc) {
    const int k = blockIdx.x, d = threadIdx.x;
    float s = 0.0f;
    for (int i = d; i < KC; i += 256) s += out[OFF_CS + i];
    #pragma unroll
    for (int off = 32; off; off >>= 1) s += __shfl_down(s, off, 64);
    __shared__ float ps[4];
    if ((d & 63) == 0) ps[d >> 6] = s;
    __syncthreads();
    const float n = ps[0] + ps[1] + ps[2] + ps[3];
    if (k == 0 && d == 0)
        out[OFF_LOSS] = 1.25f * (*lossacc) / 4194304.0f;

    const float cs = __fmul_rn(__fdiv_rn(__fadd_rn(out[OFF_CS + k], EPS_F),
                                         __fadd_rn(n, KEPS_F)), n);
    out[OFF_W + k * DD + d] = __fdiv_rn(out[OFF_EMA + k * DD + d], cs);
}

extern "C" void kernel_launch(void* const* d_in, const int* in_sizes, int n_in,
                              void* d_out, int out_size, void* d_ws, size_t ws_size,
                              hipStream_t stream) {
    const float* z    = (const float*)d_in[0];
    const float* w    = (const float*)d_in[1];
    const float* ecs  = (const float*)d_in[2];
    const float* emaw = (const float*)d_in[3];
    float* out = (float*)d_out;

    // small scratch in ws (same footprint that always passed)
    int*   idx_ws  = (int*)d_ws;                       // NTOK ints
    float* x2v     = (float*)d_ws + NTOK;              // NTOK floats
    float* w2v     = x2v + NTOK;                       // KC floats
    float* lossacc = w2v + KC;                         // 1 float

    // big scratch inside not-yet-final d_out regions:
    float* zT   = out + OFF_Q;     // 16384x256 -> 256x16384 (16 MB)
    float* wT   = out + OFF_W;     //  8192x256 -> 256x8192  ( 8 MB)
    float* vbuf = out + OFF_EMA;                        // SPLIT*NTOK floats (2 MB)
    int*   kbuf = (int*)(out + OFF_EMA) + SPLIT * NTOK; // SPLIT*NTOK ints   (2 MB)

    k_prep   <<<7680,  256, 0, stream>>>(z, w, zT, wT, x2v, w2v);
    k_argmin <<<SPLIT * (NTOK / 128), 256, 0, stream>>>(zT, wT, x2v, w2v,
                                                        vbuf, kbuf);
    k_reduce <<<NTOK / 256, 256, 0, stream>>>(vbuf, kbuf, idx_ws, out);
    k_init   <<<(KC * DD) / 256, 256, 0, stream>>>(emaw, ecs, out, lossacc);
    k_scatter<<<NTOK,  256, 0, stream>>>(z, w, idx_ws, out, lossacc);
    k_neww   <<<KC,    256, 0, stream>>>(out, lossacc);
}